// Round 3
// baseline (485.369 us; speedup 1.0000x reference)
//
#include <hip/hip_runtime.h>
#include <stdint.h>

// ---------------- problem constants ----------------
#define BB 2
#define SS 2048
#define EE 1024
#define HH 16
#define DHD 64
#define MM (BB*SS)          // 4096 tokens
// scale * log2(e): fold log2e into Q so softmax uses exp2 (v_exp_f32) directly
#define QSCALE (0.125f * 1.4426950408889634f)

typedef __bf16 bf16;
typedef __bf16 bf16x8 __attribute__((ext_vector_type(8)));
typedef __bf16 bf16x4 __attribute__((ext_vector_type(4)));
typedef float  f32x4  __attribute__((ext_vector_type(4)));
typedef unsigned short ushort8 __attribute__((ext_vector_type(8)));

#define MFMA16(a,b,c) __builtin_amdgcn_mfma_f32_16x16x32_bf16(a,b,c,0,0,0)

__device__ __forceinline__ void gload_lds16(const void* g, void* l) {
  __builtin_amdgcn_global_load_lds(
      (const __attribute__((address_space(1))) unsigned int*)g,
      (__attribute__((address_space(3))) unsigned int*)l, 16, 0, 0);
}

__device__ __forceinline__ unsigned short f2bf(float f) {
  union { float f; unsigned u; } v; v.f = f;
  return (unsigned short)((v.u + 0x7FFFu + ((v.u >> 16) & 1u)) >> 16);
}

// ---------------- kernel 0: fp32 -> bf16 conversion ----------------
// x (4M elems) + Wq,Wk,Wv,Wo (1M each). 8 elems/thread.
__global__ void convert_kernel(const float* __restrict__ x,
                               const float* __restrict__ wq, const float* __restrict__ wk,
                               const float* __restrict__ wv, const float* __restrict__ wo,
                               unsigned short* __restrict__ xbf,
                               unsigned short* __restrict__ wqb, unsigned short* __restrict__ wkb,
                               unsigned short* __restrict__ wvb, unsigned short* __restrict__ wob) {
  long t = (long)blockIdx.x * blockDim.x + threadIdx.x;  // 1M threads
  long base = t * 8;
  const float* src; unsigned short* dst; long off;
  if (base < 4194304L) { src = x; dst = xbf; off = base; }
  else {
    long r = base - 4194304L; int j = (int)(r >> 20); off = r & 1048575L;
    src = (j==0)?wq:(j==1)?wk:(j==2)?wv:wo;
    dst = (j==0)?wqb:(j==1)?wkb:(j==2)?wvb:wob;
  }
  const float4* s4 = (const float4*)(src + off);
  float4 a = s4[0], b = s4[1];
  ushort8 o;
  o[0]=f2bf(a.x); o[1]=f2bf(a.y); o[2]=f2bf(a.z); o[3]=f2bf(a.w);
  o[4]=f2bf(b.x); o[5]=f2bf(b.y); o[6]=f2bf(b.z); o[7]=f2bf(b.w);
  *(ushort8*)(dst + off) = o;
}

// ---------------- kernel 1: fused QKV projection GEMM ----------------
// C[m, n'] = x[m,:] . W[n,:] (+bias), m in [0,4096), n' in [0,3072)
// proj = n'>>10 selects (Wq,Q) / (Wk,K) / (Wv,V^T)
// 128x128 tile, BK=32, 4 waves (2x2 of 64x64), global_load_lds staging with
// source-side XOR swizzle (byte ^= (row&3)<<4) matching the ds_read side.
__global__ __launch_bounds__(256) void qkv_gemm(
    const bf16* __restrict__ xbf,
    const bf16* __restrict__ wqb, const bf16* __restrict__ wkb, const bf16* __restrict__ wvb,
    const float* __restrict__ bq, const float* __restrict__ bk, const float* __restrict__ bv,
    bf16* __restrict__ Q, bf16* __restrict__ K, bf16* __restrict__ VT) {
  __shared__ char As[128*64] __attribute__((aligned(16)));  // 128 rows x 32 bf16 (64B/row)
  __shared__ char Bs[128*64] __attribute__((aligned(16)));
  const int tid = threadIdx.x;
  const int bm = blockIdx.y * 128;
  const int bnG = blockIdx.x * 128;          // 0..3071
  const int proj = bnG >> 10;
  const int bn = bnG & 1023;
  const bf16* wsel = (proj==0)?wqb:(proj==1)?wkb:wvb;
  const float* bias = (proj==0)?bq:(proj==1)?bk:bv;

  const int lane = tid & 63, w = tid >> 6;
  const int wm = (w>>1)*64, wn = (w&1)*64;
  const int c = lane & 15, g = lane >> 4;

  // staging: inst i covers rows i*64 + (tid>>2), 16B chunk (tid&3)*16 (swizzled)
  const int sr = tid >> 2;
  const int scb = ((tid & 3) * 16) ^ ((sr & 3) << 4);
  const char* a0 = (const char*)xbf  + ((size_t)(bm + sr     ) * 1024) * 2 + scb;
  const char* a1 = (const char*)xbf  + ((size_t)(bm + 64 + sr) * 1024) * 2 + scb;
  const char* b0 = (const char*)wsel + ((size_t)(bn + sr     ) * 1024) * 2 + scb;
  const char* b1 = (const char*)wsel + ((size_t)(bn + 64 + sr) * 1024) * 2 + scb;
  char* lA0 = As + tid*16; char* lA1 = As + 4096 + tid*16;
  char* lB0 = Bs + tid*16; char* lB1 = Bs + 4096 + tid*16;

  int aoff[4], boff[4];
#pragma unroll
  for (int mt=0; mt<4; ++mt) { int rr = wm + mt*16 + c; aoff[mt] = rr*64 + ((g*16) ^ ((rr&3)<<4)); }
#pragma unroll
  for (int nt=0; nt<4; ++nt) { int rr = wn + nt*16 + c; boff[nt] = rr*64 + ((g*16) ^ ((rr&3)<<4)); }

  f32x4 acc[4][4];
#pragma unroll
  for (int mt=0; mt<4; ++mt)
#pragma unroll
    for (int nt=0; nt<4; ++nt) acc[mt][nt] = (f32x4){0.f,0.f,0.f,0.f};

  for (int kt = 0; kt < 32; ++kt) {
    const size_t kb = (size_t)kt * 64;   // 32 bf16 = 64 bytes per K-step
    gload_lds16(a0 + kb, lA0); gload_lds16(a1 + kb, lA1);
    gload_lds16(b0 + kb, lB0); gload_lds16(b1 + kb, lB1);
    __syncthreads();                      // drains vmcnt -> LDS tile ready
    bf16x8 af[4], bfv[4];
#pragma unroll
    for (int mt=0; mt<4; ++mt) af[mt] = *(const bf16x8*)(As + aoff[mt]);
#pragma unroll
    for (int nt=0; nt<4; ++nt) bfv[nt] = *(const bf16x8*)(Bs + boff[nt]);
#pragma unroll
    for (int mt=0; mt<4; ++mt)
#pragma unroll
      for (int nt=0; nt<4; ++nt)
        acc[mt][nt] = MFMA16(af[mt], bfv[nt], acc[mt][nt]);
    __syncthreads();                      // protect LDS before next stage
  }

  // epilogue: D layout col=lane&15, row=(lane>>4)*4+r
  const int bidx = bm >> 11;
  const int srow = bm & 2047;
#pragma unroll
  for (int nt=0; nt<4; ++nt) {
    const int n = bn + wn + nt*16 + c;    // 0..1023 within this projection
    const float bv_ = bias[n];
    const int h = n >> 6, d = n & 63;
#pragma unroll
    for (int mt=0; mt<4; ++mt) {
      f32x4 a = acc[mt][nt];
      const int m0 = wm + mt*16 + g*4;
      if (proj == 0) {
#pragma unroll
        for (int r=0;r<4;++r) {
          int s = srow + m0 + r;
          Q[(((size_t)(bidx*16 + h))*2048 + s)*64 + d] = (bf16)((a[r] + bv_) * QSCALE);
        }
      } else if (proj == 1) {
#pragma unroll
        for (int r=0;r<4;++r) {
          int s = srow + m0 + r;
          K[(((size_t)(bidx*16 + h))*2048 + s)*64 + d] = (bf16)(a[r] + bv_);
        }
      } else {
        bf16x4 pk;
#pragma unroll
        for (int r=0;r<4;++r) pk[r] = (bf16)(a[r] + bv_);
        *(bf16x4*)(VT + (((size_t)(bidx*16 + h))*64 + d)*2048 + (srow + m0)) = pk;
      }
    }
  }
}

// ---------------- kernel 2: flash attention ----------------
// grid = (S/64, B*H). 4 waves/block, each wave owns 16 q-rows. No LDS:
// per-head K/V (512 KB) is L2-resident. Swapped QK^T: scores^T frag has
// col=lane&15=q, row=key -> softmax row-reduce is in-lane + 2 shfl_xor.
// PV uses permuted-k: V^T read in the P-fragment's natural key order.
__global__ __launch_bounds__(256) void attn_kernel(
    const bf16* __restrict__ Q, const bf16* __restrict__ K,
    const bf16* __restrict__ VT, bf16* __restrict__ attn_out) {
  const int tid = threadIdx.x;
  const int lane = tid & 63, w = tid >> 6;
  const int c = lane & 15, g = lane >> 4;
  const int bh = blockIdx.y;                      // b*16 + h
  const int qb = blockIdx.x * 64 + w * 16;        // wave's q base
  const bf16* Qh = Q  + (size_t)bh * 2048 * 64;
  const bf16* Kh = K  + (size_t)bh * 2048 * 64;
  const bf16* Vh = VT + (size_t)bh * 64 * 2048;

  // Q fragments (B-operand): lane holds q = qb+c, 8 contiguous d at (g*8 + kk*32)
  bf16x8 qf0 = *(const bf16x8*)(Qh + (size_t)(qb + c)*64 + g*8);
  bf16x8 qf1 = *(const bf16x8*)(Qh + (size_t)(qb + c)*64 + 32 + g*8);

  f32x4 o0 = (f32x4){0,0,0,0}, o1 = (f32x4){0,0,0,0};
  f32x4 o2 = (f32x4){0,0,0,0}, o3 = (f32x4){0,0,0,0};
  float m = -1e30f, l = 0.f;

  for (int kv = 0; kv < 2048; kv += 32) {
    // scores^T: D[row=key][col=q], A = K rows (row=lane&15), k = d
    const bf16* kb = Kh + (size_t)kv * 64;
    bf16x8 k00 = *(const bf16x8*)(kb + (size_t)(c     )*64      + g*8);
    bf16x8 k01 = *(const bf16x8*)(kb + (size_t)(c     )*64 + 32 + g*8);
    bf16x8 k10 = *(const bf16x8*)(kb + (size_t)(16 + c)*64      + g*8);
    bf16x8 k11 = *(const bf16x8*)(kb + (size_t)(16 + c)*64 + 32 + g*8);
    f32x4 st0 = (f32x4){0,0,0,0}, st1 = (f32x4){0,0,0,0};
    st0 = MFMA16(k00, qf0, st0); st0 = MFMA16(k01, qf1, st0);
    st1 = MFMA16(k10, qf0, st1); st1 = MFMA16(k11, qf1, st1);

    // online softmax (scores already in log2 domain via QSCALE)
    float tmax = fmaxf(fmaxf(fmaxf(st0[0],st0[1]), fmaxf(st0[2],st0[3])),
                       fmaxf(fmaxf(st1[0],st1[1]), fmaxf(st1[2],st1[3])));
    tmax = fmaxf(tmax, __shfl_xor(tmax, 16, 64));
    tmax = fmaxf(tmax, __shfl_xor(tmax, 32, 64));
    const float mnew = fmaxf(m, tmax);
    const float corr = __builtin_exp2f(m - mnew);
    float p0[4], p1[4], ps = 0.f;
#pragma unroll
    for (int r=0;r<4;++r) { p0[r] = __builtin_exp2f(st0[r] - mnew); ps += p0[r]; }
#pragma unroll
    for (int r=0;r<4;++r) { p1[r] = __builtin_exp2f(st1[r] - mnew); ps += p1[r]; }
    ps += __shfl_xor(ps, 16, 64);
    ps += __shfl_xor(ps, 32, 64);
    l = l * corr + ps;
    m = mnew;
    o0 *= corr; o1 *= corr; o2 *= corr; o3 *= corr;

    // P fragment (B-operand), keys in per-lane natural order:
    // element j (<4): key = 4g+j ; element j (>=4): key = 16+4g+(j-4)
    bf16x8 pf;
    pf[0]=(bf16)p0[0]; pf[1]=(bf16)p0[1]; pf[2]=(bf16)p0[2]; pf[3]=(bf16)p0[3];
    pf[4]=(bf16)p1[0]; pf[5]=(bf16)p1[1]; pf[6]=(bf16)p1[2]; pf[7]=(bf16)p1[3];

    // PV: O^T[d][q] += V^T[d][key] * P^T[key][q], same key permutation on A side
#pragma unroll
    for (int dt=0; dt<4; ++dt) {
      const bf16* vb = Vh + (size_t)(dt*16 + c)*2048 + kv;
      bf16x4 v0 = *(const bf16x4*)(vb + 4*g);
      bf16x4 v1 = *(const bf16x4*)(vb + 16 + 4*g);
      bf16x8 vf = __builtin_shufflevector(v0, v1, 0,1,2,3,4,5,6,7);
      if      (dt==0) o0 = MFMA16(vf, pf, o0);
      else if (dt==1) o1 = MFMA16(vf, pf, o1);
      else if (dt==2) o2 = MFMA16(vf, pf, o2);
      else            o3 = MFMA16(vf, pf, o3);
    }
  }

  const float inv = 1.0f / l;
  const int srow = qb + c;                        // this lane's token s
  const int b = bh >> 4, h = bh & 15;
  bf16* outrow = attn_out + ((size_t)(b*2048 + srow))*1024 + h*64;
  f32x4 oo[4] = {o0, o1, o2, o3};
#pragma unroll
  for (int dt=0; dt<4; ++dt) {
    bf16x4 ov;
#pragma unroll
    for (int r=0;r<4;++r) ov[r] = (bf16)(oo[dt][r] * inv);
    *(bf16x4*)(outrow + dt*16 + g*4) = ov;
  }
}

// ---------------- kernel 3: output projection GEMM (fp32 out + bias) ----------------
__global__ __launch_bounds__(256) void out_gemm(
    const bf16* __restrict__ A, const bf16* __restrict__ W,
    const float* __restrict__ bias, float* __restrict__ out) {
  __shared__ char As[128*64] __attribute__((aligned(16)));
  __shared__ char Bs[128*64] __attribute__((aligned(16)));
  const int tid = threadIdx.x;
  const int bm = blockIdx.y * 128, bn = blockIdx.x * 128;
  const int lane = tid & 63, w = tid >> 6;
  const int wm = (w>>1)*64, wn = (w&1)*64;
  const int c = lane & 15, g = lane >> 4;

  const int sr = tid >> 2;
  const int scb = ((tid & 3) * 16) ^ ((sr & 3) << 4);
  const char* a0 = (const char*)A + ((size_t)(bm + sr     ) * 1024) * 2 + scb;
  const char* a1 = (const char*)A + ((size_t)(bm + 64 + sr) * 1024) * 2 + scb;
  const char* b0 = (const char*)W + ((size_t)(bn + sr     ) * 1024) * 2 + scb;
  const char* b1 = (const char*)W + ((size_t)(bn + 64 + sr) * 1024) * 2 + scb;
  char* lA0 = As + tid*16; char* lA1 = As + 4096 + tid*16;
  char* lB0 = Bs + tid*16; char* lB1 = Bs + 4096 + tid*16;

  int aoff[4], boff[4];
#pragma unroll
  for (int mt=0; mt<4; ++mt) { int rr = wm + mt*16 + c; aoff[mt] = rr*64 + ((g*16) ^ ((rr&3)<<4)); }
#pragma unroll
  for (int nt=0; nt<4; ++nt) { int rr = wn + nt*16 + c; boff[nt] = rr*64 + ((g*16) ^ ((rr&3)<<4)); }

  f32x4 acc[4][4];
#pragma unroll
  for (int mt=0; mt<4; ++mt)
#pragma unroll
    for (int nt=0; nt<4; ++nt) acc[mt][nt] = (f32x4){0.f,0.f,0.f,0.f};

  for (int kt = 0; kt < 32; ++kt) {
    const size_t kb = (size_t)kt * 64;
    gload_lds16(a0 + kb, lA0); gload_lds16(a1 + kb, lA1);
    gload_lds16(b0 + kb, lB0); gload_lds16(b1 + kb, lB1);
    __syncthreads();
    bf16x8 af[4], bfv[4];
#pragma unroll
    for (int mt=0; mt<4; ++mt) af[mt] = *(const bf16x8*)(As + aoff[mt]);
#pragma unroll
    for (int nt=0; nt<4; ++nt) bfv[nt] = *(const bf16x8*)(Bs + boff[nt]);
#pragma unroll
    for (int mt=0; mt<4; ++mt)
#pragma unroll
      for (int nt=0; nt<4; ++nt)
        acc[mt][nt] = MFMA16(af[mt], bfv[nt], acc[mt][nt]);
    __syncthreads();
  }

#pragma unroll
  for (int nt=0; nt<4; ++nt) {
    const int n = bn + wn + nt*16 + c;
    const float bv_ = bias[n];
#pragma unroll
    for (int mt=0; mt<4; ++mt) {
      const int m0 = bm + wm + mt*16 + g*4;
#pragma unroll
      for (int r=0;r<4;++r) out[(size_t)(m0 + r)*1024 + n] = acc[mt][nt][r] + bv_;
    }
  }
}

// ---------------- launch ----------------
extern "C" void kernel_launch(void* const* d_in, const int* in_sizes, int n_in,
                              void* d_out, int out_size, void* d_ws, size_t ws_size,
                              hipStream_t stream) {
  const float* x  = (const float*)d_in[0];
  const float* Wq = (const float*)d_in[1];
  const float* bq = (const float*)d_in[2];
  const float* Wk = (const float*)d_in[3];
  const float* bk = (const float*)d_in[4];
  const float* Wv = (const float*)d_in[5];
  const float* bv = (const float*)d_in[6];
  const float* Wo = (const float*)d_in[7];
  const float* bo = (const float*)d_in[8];

  char* ws = (char*)d_ws;
  const size_t MiB = 1u << 20;
  unsigned short* xbf = (unsigned short*)(ws);              // 8 MiB
  unsigned short* wqb = (unsigned short*)(ws +  8*MiB);     // 2 MiB
  unsigned short* wkb = (unsigned short*)(ws + 10*MiB);
  unsigned short* wvb = (unsigned short*)(ws + 12*MiB);
  unsigned short* wob = (unsigned short*)(ws + 14*MiB);
  bf16* Qb    = (bf16*)(ws + 16*MiB);                       // 8 MiB [B,H,S,DH]
  bf16* Kb    = (bf16*)(ws + 24*MiB);                       // 8 MiB [B,H,S,DH]
  bf16* VTb   = (bf16*)(ws + 32*MiB);                       // 8 MiB [B,H,DH,S]
  bf16* attnb = (bf16*)(ws + 40*MiB);                       // 8 MiB [M,E]

  convert_kernel<<<4096, 256, 0, stream>>>(x, Wq, Wk, Wv, Wo, xbf, wqb, wkb, wvb, wob);
  qkv_gemm<<<dim3(24, 32), 256, 0, stream>>>(
      (const bf16*)xbf, (const bf16*)wqb, (const bf16*)wkb, (const bf16*)wvb,
      bq, bk, bv, Qb, Kb, VTb);
  attn_kernel<<<dim3(32, 32), 256, 0, stream>>>(Qb, Kb, VTb, attnb);
  out_gemm<<<dim3(8, 32), 256, 0, stream>>>(attnb, (const bf16*)wob, bo, (float*)d_out);
}

// Round 4
// 230.328 us; speedup vs baseline: 2.1073x; 2.1073x over previous
//
#include <hip/hip_runtime.h>
#include <stdint.h>

// ---------------- problem constants ----------------
#define BB 2
#define SS 2048
#define EE 1024
#define HH 16
#define DHD 64
#define MM (BB*SS)          // 4096 tokens
// scale * log2(e): fold log2e into Q so softmax uses exp2 (v_exp_f32) directly
#define QSCALE (0.125f * 1.4426950408889634f)

typedef __bf16 bf16;
typedef __bf16 bf16x8 __attribute__((ext_vector_type(8)));
typedef __bf16 bf16x4 __attribute__((ext_vector_type(4)));
typedef float  f32x4  __attribute__((ext_vector_type(4)));
typedef unsigned short ushort8 __attribute__((ext_vector_type(8)));

#define MFMA16(a,b,c) __builtin_amdgcn_mfma_f32_16x16x32_bf16(a,b,c,0,0,0)

__device__ __forceinline__ void gload_lds16(const void* g, void* l) {
  __builtin_amdgcn_global_load_lds(
      (const __attribute__((address_space(1))) unsigned int*)g,
      (__attribute__((address_space(3))) unsigned int*)l, 16, 0, 0);
}

__device__ __forceinline__ unsigned short f2bf(float f) {
  union { float f; unsigned u; } v; v.f = f;
  return (unsigned short)((v.u + 0x7FFFu + ((v.u >> 16) & 1u)) >> 16);
}

// ---------------- kernel 0: fp32 -> bf16 conversion ----------------
__global__ void convert_kernel(const float* __restrict__ x,
                               const float* __restrict__ wq, const float* __restrict__ wk,
                               const float* __restrict__ wv, const float* __restrict__ wo,
                               unsigned short* __restrict__ xbf,
                               unsigned short* __restrict__ wqb, unsigned short* __restrict__ wkb,
                               unsigned short* __restrict__ wvb, unsigned short* __restrict__ wob) {
  long t = (long)blockIdx.x * blockDim.x + threadIdx.x;  // 1M threads
  long base = t * 8;
  const float* src; unsigned short* dst; long off;
  if (base < 4194304L) { src = x; dst = xbf; off = base; }
  else {
    long r = base - 4194304L; int j = (int)(r >> 20); off = r & 1048575L;
    src = (j==0)?wq:(j==1)?wk:(j==2)?wv:wo;
    dst = (j==0)?wqb:(j==1)?wkb:(j==2)?wvb:wob;
  }
  const float4* s4 = (const float4*)(src + off);
  float4 a = s4[0], b = s4[1];
  ushort8 o;
  o[0]=f2bf(a.x); o[1]=f2bf(a.y); o[2]=f2bf(a.z); o[3]=f2bf(a.w);
  o[4]=f2bf(b.x); o[5]=f2bf(b.y); o[6]=f2bf(b.z); o[7]=f2bf(b.w);
  *(ushort8*)(dst + off) = o;
}

// ---------------- kernel 1: fused QKV projection GEMM (unchanged) ----------------
__global__ __launch_bounds__(256) void qkv_gemm(
    const bf16* __restrict__ xbf,
    const bf16* __restrict__ wqb, const bf16* __restrict__ wkb, const bf16* __restrict__ wvb,
    const float* __restrict__ bq, const float* __restrict__ bk, const float* __restrict__ bv,
    bf16* __restrict__ Q, bf16* __restrict__ K, bf16* __restrict__ VT) {
  __shared__ char As[128*64] __attribute__((aligned(16)));
  __shared__ char Bs[128*64] __attribute__((aligned(16)));
  const int tid = threadIdx.x;
  const int bm = blockIdx.y * 128;
  const int bnG = blockIdx.x * 128;
  const int proj = bnG >> 10;
  const int bn = bnG & 1023;
  const bf16* wsel = (proj==0)?wqb:(proj==1)?wkb:wvb;
  const float* bias = (proj==0)?bq:(proj==1)?bk:bv;

  const int lane = tid & 63, w = tid >> 6;
  const int wm = (w>>1)*64, wn = (w&1)*64;
  const int c = lane & 15, g = lane >> 4;

  const int sr = tid >> 2;
  const int scb = ((tid & 3) * 16) ^ ((sr & 3) << 4);
  const char* a0 = (const char*)xbf  + ((size_t)(bm + sr     ) * 1024) * 2 + scb;
  const char* a1 = (const char*)xbf  + ((size_t)(bm + 64 + sr) * 1024) * 2 + scb;
  const char* b0 = (const char*)wsel + ((size_t)(bn + sr     ) * 1024) * 2 + scb;
  const char* b1 = (const char*)wsel + ((size_t)(bn + 64 + sr) * 1024) * 2 + scb;
  char* lA0 = As + tid*16; char* lA1 = As + 4096 + tid*16;
  char* lB0 = Bs + tid*16; char* lB1 = Bs + 4096 + tid*16;

  int aoff[4], boff[4];
#pragma unroll
  for (int mt=0; mt<4; ++mt) { int rr = wm + mt*16 + c; aoff[mt] = rr*64 + ((g*16) ^ ((rr&3)<<4)); }
#pragma unroll
  for (int nt=0; nt<4; ++nt) { int rr = wn + nt*16 + c; boff[nt] = rr*64 + ((g*16) ^ ((rr&3)<<4)); }

  f32x4 acc[4][4];
#pragma unroll
  for (int mt=0; mt<4; ++mt)
#pragma unroll
    for (int nt=0; nt<4; ++nt) acc[mt][nt] = (f32x4){0.f,0.f,0.f,0.f};

  for (int kt = 0; kt < 32; ++kt) {
    const size_t kb = (size_t)kt * 64;
    gload_lds16(a0 + kb, lA0); gload_lds16(a1 + kb, lA1);
    gload_lds16(b0 + kb, lB0); gload_lds16(b1 + kb, lB1);
    __syncthreads();
    bf16x8 af[4], bfv[4];
#pragma unroll
    for (int mt=0; mt<4; ++mt) af[mt] = *(const bf16x8*)(As + aoff[mt]);
#pragma unroll
    for (int nt=0; nt<4; ++nt) bfv[nt] = *(const bf16x8*)(Bs + boff[nt]);
#pragma unroll
    for (int mt=0; mt<4; ++mt)
#pragma unroll
      for (int nt=0; nt<4; ++nt)
        acc[mt][nt] = MFMA16(af[mt], bfv[nt], acc[mt][nt]);
    __syncthreads();
  }

  const int bidx = bm >> 11;
  const int srow = bm & 2047;
#pragma unroll
  for (int nt=0; nt<4; ++nt) {
    const int n = bn + wn + nt*16 + c;
    const float bv_ = bias[n];
    const int h = n >> 6, d = n & 63;
#pragma unroll
    for (int mt=0; mt<4; ++mt) {
      f32x4 a = acc[mt][nt];
      const int m0 = wm + mt*16 + g*4;
      if (proj == 0) {
#pragma unroll
        for (int r=0;r<4;++r) {
          int s = srow + m0 + r;
          Q[(((size_t)(bidx*16 + h))*2048 + s)*64 + d] = (bf16)((a[r] + bv_) * QSCALE);
        }
      } else if (proj == 1) {
#pragma unroll
        for (int r=0;r<4;++r) {
          int s = srow + m0 + r;
          K[(((size_t)(bidx*16 + h))*2048 + s)*64 + d] = (bf16)(a[r] + bv_);
        }
      } else {
        bf16x4 pk;
#pragma unroll
        for (int r=0;r<4;++r) pk[r] = (bf16)(a[r] + bv_);
        *(bf16x4*)(VT + (((size_t)(bidx*16 + h))*64 + d)*2048 + (srow + m0)) = pk;
      }
    }
  }
}

// ---------------- kernel 2: flash attention v2 (LDS-shared K/V, dbuf) ----------------
// grid = (S/64, B*H), 4 waves/block, wave owns 16 q-rows. KVBLK=64.
// K tile [64 keys][64 d] and V tile [64 d][64 keys] staged to LDS via
// global_load_lds (shared across the 4 waves), double-buffered with counted
// vmcnt(4) + raw s_barrier (prefetch stays in flight across the barrier).
// 16B-chunk XOR swizzle (chunk ^= row&7) on both stage-source and ds_read.
__global__ __launch_bounds__(256) void attn_kernel(
    const bf16* __restrict__ Q, const bf16* __restrict__ K,
    const bf16* __restrict__ VT, bf16* __restrict__ attn_out) {
  __shared__ char lds[32768] __attribute__((aligned(16)));
  const int tid = threadIdx.x;
  const int lane = tid & 63, w = tid >> 6;
  const int c = lane & 15, g = lane >> 4;
  const int x7 = c & 7;
  const int bh = blockIdx.y;                      // b*16 + h
  const int qb = blockIdx.x * 64 + w * 16;        // wave's q base
  const bf16* Qh = Q + (size_t)bh * 2048 * 64;
  const char* Khb = (const char*)(K  + (size_t)bh * 2048 * 64);
  const char* Vhb = (const char*)(VT + (size_t)bh * 64 * 2048);

  // staging: thread covers LDS bytes [tid*16, +16) of each 4KB half-tile.
  // LDS(row, chunk) <- global(row, chunk ^ (row&7));  row = tid>>3, chunk = tid&7.
  const int srow = tid >> 3, schunk = tid & 7;
  const int ssw = ((schunk ^ (srow & 7)) << 4);
  const char* srcK = Khb + (size_t)srow * 128  + ssw;   // + kv*128 ; +32*128 for rows 32-63
  const char* srcV = Vhb + (size_t)srow * 4096 + ssw;   // + kv*2   ; +32*4096

#define ATT_STAGE(buf, kv) { \
    const char* sk_ = srcK + (size_t)(kv) * 128; \
    const char* sv_ = srcV + (size_t)(kv) * 2; \
    char* d_ = lds + (buf) * 16384 + tid * 16; \
    gload_lds16(sk_,            d_); \
    gload_lds16(sk_ + 32*128,   d_ + 4096); \
    gload_lds16(sv_,            d_ + 8192); \
    gload_lds16(sv_ + 32*4096,  d_ + 12288); \
  }

  // Q fragments (B-operand): lane holds q = qb+c, d = kk*32 + g*8 + j
  bf16x8 qf0 = *(const bf16x8*)(Qh + (size_t)(qb + c)*64 + g*8);
  bf16x8 qf1 = *(const bf16x8*)(Qh + (size_t)(qb + c)*64 + 32 + g*8);

  f32x4 o[4];
#pragma unroll
  for (int dt=0; dt<4; ++dt) o[dt] = (f32x4){0.f,0.f,0.f,0.f};
  float m = -1e30f, l = 0.f;

  ATT_STAGE(0, 0);
  for (int t = 0; t < 32; ++t) {
    const int cur = t & 1;
    if (t < 31) {
      ATT_STAGE(cur ^ 1, (t + 1) * 64);
      asm volatile("s_waitcnt vmcnt(4)" ::: "memory");   // my 4 cur-tile loads done
    } else {
      asm volatile("s_waitcnt vmcnt(0)" ::: "memory");
    }
    __builtin_amdgcn_s_barrier();                        // all waves' cur tile ready

    const char* Kl = lds + cur * 16384;
    const char* Vl = Kl + 8192;

    // QK^T (swapped): st[ks] holds scores for keys ks*16 + 4g + r, q = qb+c
    f32x4 st[4];
#pragma unroll
    for (int ks = 0; ks < 4; ++ks) {
      const char* kr = Kl + (ks*16 + c) * 128;
      bf16x8 k0 = *(const bf16x8*)(kr + (((g    ) ^ x7) << 4));
      bf16x8 k1 = *(const bf16x8*)(kr + (((g + 4) ^ x7) << 4));
      f32x4 z = (f32x4){0.f,0.f,0.f,0.f};
      z = MFMA16(k0, qf0, z);
      z = MFMA16(k1, qf1, z);
      st[ks] = z;
    }

    // online softmax over 64 keys (scores in log2 domain via QSCALE)
    float tmax = -1e30f;
#pragma unroll
    for (int ks = 0; ks < 4; ++ks)
      tmax = fmaxf(tmax, fmaxf(fmaxf(st[ks][0], st[ks][1]), fmaxf(st[ks][2], st[ks][3])));
    tmax = fmaxf(tmax, __shfl_xor(tmax, 16, 64));
    tmax = fmaxf(tmax, __shfl_xor(tmax, 32, 64));
    const float mnew = fmaxf(m, tmax);
    const float corr = __builtin_exp2f(m - mnew);
    float p[4][4]; float ps = 0.f;
#pragma unroll
    for (int ks = 0; ks < 4; ++ks)
#pragma unroll
      for (int r = 0; r < 4; ++r) { p[ks][r] = __builtin_exp2f(st[ks][r] - mnew); ps += p[ks][r]; }
    ps += __shfl_xor(ps, 16, 64);
    ps += __shfl_xor(ps, 32, 64);
    l = l * corr + ps;
    m = mnew;
#pragma unroll
    for (int dt=0; dt<4; ++dt) o[dt] *= corr;

    // P fragments, permuted-k (lane-local): slot (g,j<4) = key 4g+j (+16 for j>=4)
    bf16x8 pfA, pfB;
#pragma unroll
    for (int r = 0; r < 4; ++r) {
      pfA[r] = (bf16)p[0][r]; pfA[4+r] = (bf16)p[1][r];
      pfB[r] = (bf16)p[2][r]; pfB[4+r] = (bf16)p[3][r];
    }

    // PV: O^T[d][q] += V^T[d][key]*P^T[key][q]; V read with same key permutation
#pragma unroll
    for (int dt = 0; dt < 4; ++dt) {
      const char* vr = Vl + (dt*16 + c) * 128;
      const int i8 = (g & 1) * 8, gh = g >> 1;
      bf16x4 a0 = *(const bf16x4*)(vr + (((gh    ) ^ x7) << 4) + i8);   // keys  4g..
      bf16x4 a1 = *(const bf16x4*)(vr + (((gh + 2) ^ x7) << 4) + i8);   // keys 16+4g..
      bf16x4 b0 = *(const bf16x4*)(vr + (((gh + 4) ^ x7) << 4) + i8);   // keys 32+4g..
      bf16x4 b1 = *(const bf16x4*)(vr + (((gh + 6) ^ x7) << 4) + i8);   // keys 48+4g..
      bf16x8 vfA = __builtin_shufflevector(a0, a1, 0,1,2,3,4,5,6,7);
      bf16x8 vfB = __builtin_shufflevector(b0, b1, 0,1,2,3,4,5,6,7);
      o[dt] = MFMA16(vfA, pfA, o[dt]);
      o[dt] = MFMA16(vfB, pfB, o[dt]);
    }

    asm volatile("s_waitcnt lgkmcnt(0)" ::: "memory");   // all my LDS reads retired
    __builtin_amdgcn_s_barrier();                        // safe to overwrite cur next iter
  }
#undef ATT_STAGE

  const float inv = 1.0f / l;
  const int srow_q = qb + c;
  const int b = bh >> 4, h = bh & 15;
  bf16* outrow = attn_out + ((size_t)(b*2048 + srow_q))*1024 + h*64;
#pragma unroll
  for (int dt=0; dt<4; ++dt) {
    bf16x4 ov;
#pragma unroll
    for (int r=0;r<4;++r) ov[r] = (bf16)(o[dt][r] * inv);
    *(bf16x4*)(outrow + dt*16 + g*4) = ov;
  }
}

// ---------------- kernel 3: output projection GEMM (unchanged) ----------------
__global__ __launch_bounds__(256) void out_gemm(
    const bf16* __restrict__ A, const bf16* __restrict__ W,
    const float* __restrict__ bias, float* __restrict__ out) {
  __shared__ char As[128*64] __attribute__((aligned(16)));
  __shared__ char Bs[128*64] __attribute__((aligned(16)));
  const int tid = threadIdx.x;
  const int bm = blockIdx.y * 128, bn = blockIdx.x * 128;
  const int lane = tid & 63, w = tid >> 6;
  const int wm = (w>>1)*64, wn = (w&1)*64;
  const int c = lane & 15, g = lane >> 4;

  const int sr = tid >> 2;
  const int scb = ((tid & 3) * 16) ^ ((sr & 3) << 4);
  const char* a0 = (const char*)A + ((size_t)(bm + sr     ) * 1024) * 2 + scb;
  const char* a1 = (const char*)A + ((size_t)(bm + 64 + sr) * 1024) * 2 + scb;
  const char* b0 = (const char*)W + ((size_t)(bn + sr     ) * 1024) * 2 + scb;
  const char* b1 = (const char*)W + ((size_t)(bn + 64 + sr) * 1024) * 2 + scb;
  char* lA0 = As + tid*16; char* lA1 = As + 4096 + tid*16;
  char* lB0 = Bs + tid*16; char* lB1 = Bs + 4096 + tid*16;

  int aoff[4], boff[4];
#pragma unroll
  for (int mt=0; mt<4; ++mt) { int rr = wm + mt*16 + c; aoff[mt] = rr*64 + ((g*16) ^ ((rr&3)<<4)); }
#pragma unroll
  for (int nt=0; nt<4; ++nt) { int rr = wn + nt*16 + c; boff[nt] = rr*64 + ((g*16) ^ ((rr&3)<<4)); }

  f32x4 acc[4][4];
#pragma unroll
  for (int mt=0; mt<4; ++mt)
#pragma unroll
    for (int nt=0; nt<4; ++nt) acc[mt][nt] = (f32x4){0.f,0.f,0.f,0.f};

  for (int kt = 0; kt < 32; ++kt) {
    const size_t kb = (size_t)kt * 64;
    gload_lds16(a0 + kb, lA0); gload_lds16(a1 + kb, lA1);
    gload_lds16(b0 + kb, lB0); gload_lds16(b1 + kb, lB1);
    __syncthreads();
    bf16x8 af[4], bfv[4];
#pragma unroll
    for (int mt=0; mt<4; ++mt) af[mt] = *(const bf16x8*)(As + aoff[mt]);
#pragma unroll
    for (int nt=0; nt<4; ++nt) bfv[nt] = *(const bf16x8*)(Bs + boff[nt]);
#pragma unroll
    for (int mt=0; mt<4; ++mt)
#pragma unroll
      for (int nt=0; nt<4; ++nt)
        acc[mt][nt] = MFMA16(af[mt], bfv[nt], acc[mt][nt]);
    __syncthreads();
  }

#pragma unroll
  for (int nt=0; nt<4; ++nt) {
    const int n = bn + wn + nt*16 + c;
    const float bv_ = bias[n];
#pragma unroll
    for (int mt=0; mt<4; ++mt) {
      const int m0 = bm + wm + mt*16 + g*4;
#pragma unroll
      for (int r=0;r<4;++r) out[(size_t)(m0 + r)*1024 + n] = acc[mt][nt][r] + bv_;
    }
  }
}

// ---------------- launch ----------------
extern "C" void kernel_launch(void* const* d_in, const int* in_sizes, int n_in,
                              void* d_out, int out_size, void* d_ws, size_t ws_size,
                              hipStream_t stream) {
  const float* x  = (const float*)d_in[0];
  const float* Wq = (const float*)d_in[1];
  const float* bq = (const float*)d_in[2];
  const float* Wk = (const float*)d_in[3];
  const float* bk = (const float*)d_in[4];
  const float* Wv = (const float*)d_in[5];
  const float* bv = (const float*)d_in[6];
  const float* Wo = (const float*)d_in[7];
  const float* bo = (const float*)d_in[8];

  char* ws = (char*)d_ws;
  const size_t MiB = 1u << 20;
  unsigned short* xbf = (unsigned short*)(ws);              // 8 MiB
  unsigned short* wqb = (unsigned short*)(ws +  8*MiB);     // 2 MiB
  unsigned short* wkb = (unsigned short*)(ws + 10*MiB);
  unsigned short* wvb = (unsigned short*)(ws + 12*MiB);
  unsigned short* wob = (unsigned short*)(ws + 14*MiB);
  bf16* Qb    = (bf16*)(ws + 16*MiB);                       // 8 MiB [B,H,S,DH]
  bf16* Kb    = (bf16*)(ws + 24*MiB);                       // 8 MiB [B,H,S,DH]
  bf16* VTb   = (bf16*)(ws + 32*MiB);                       // 8 MiB [B,H,DH,S]
  bf16* attnb = (bf16*)(ws + 40*MiB);                       // 8 MiB [M,E]

  convert_kernel<<<4096, 256, 0, stream>>>(x, Wq, Wk, Wv, Wo, xbf, wqb, wkb, wvb, wob);
  qkv_gemm<<<dim3(24, 32), 256, 0, stream>>>(
      (const bf16*)xbf, (const bf16*)wqb, (const bf16*)wkb, (const bf16*)wvb,
      bq, bk, bv, Qb, Kb, VTb);
  attn_kernel<<<dim3(32, 32), 256, 0, stream>>>(Qb, Kb, VTb, attnb);
  out_gemm<<<dim3(8, 32), 256, 0, stream>>>(attnb, (const bf16*)wob, bo, (float*)d_out);
}